// Round 4
// baseline (1163.906 us; speedup 1.0000x reference)
//
#include <hip/hip_runtime.h>
#include <hip/hip_bf16.h>

// DSS bundle propagation: 3 graphs x (2-layer SpMM + L2norm + average).
// R3: CSR build rewritten to kill scatter write-amplification (125 MB HBM
// writes for a 16 MB buffer in R2 counters):
//   pass A: k-pass row-window-filtered scatter of 4-B edge indices (perm)
//           -> live write window ~2 MB -> L2 merges lines
//   pass B: coalesced gather ev[p] = {col,val}[perm[p]]
// SpMM kernels unchanged (4-deep pipelined gather, fused epilogue).
//
// Output rows: [UI_u(U) | UB_u(U) | BI_b(NB) | UB_b(NB) | UI_i(NI) | BI_i(NI)]

#define D 64

// ---------- CSR build ----------
__global__ void count_rows(const int* __restrict__ rows, int E, int* __restrict__ cnt) {
    int e = blockIdx.x * blockDim.x + threadIdx.x;
    if (e < E) atomicAdd(&cnt[rows[e]], 1);
}

__global__ void scan_block(const int* __restrict__ cnt, int n,
                           int* __restrict__ row_ptr, int* __restrict__ bsum) {
    __shared__ int s[256];
    int tid = threadIdx.x;
    int i = blockIdx.x * 256 + tid;
    int v = (i < n) ? cnt[i] : 0;
    s[tid] = v;
    __syncthreads();
    #pragma unroll
    for (int off = 1; off < 256; off <<= 1) {
        int t = (tid >= off) ? s[tid - off] : 0;
        __syncthreads();
        s[tid] += t;
        __syncthreads();
    }
    if (i < n) row_ptr[i] = s[tid] - v;
    if (tid == 255) bsum[blockIdx.x] = s[255];
}

__global__ void scan_bsums(int* __restrict__ bsum, int nb) {
    __shared__ int s[1024];
    __shared__ int carry_s;
    int tid = threadIdx.x;
    if (tid == 0) carry_s = 0;
    __syncthreads();
    for (int base = 0; base < nb; base += 1024) {
        int i = base + tid;
        int v = (i < nb) ? bsum[i] : 0;
        s[tid] = v;
        __syncthreads();
        for (int off = 1; off < 1024; off <<= 1) {
            int t = (tid >= off) ? s[tid - off] : 0;
            __syncthreads();
            s[tid] += t;
            __syncthreads();
        }
        if (i < nb) bsum[i] = carry_s + s[tid] - v;
        __syncthreads();
        if (tid == 1023) carry_s += s[1023];
        __syncthreads();
    }
}

__global__ void add_offsets(int* __restrict__ row_ptr, const int* __restrict__ bsum,
                            int n, int E) {
    int i = blockIdx.x * blockDim.x + threadIdx.x;
    if (i < n) row_ptr[i] += bsum[i >> 8];
    if (i == 0) row_ptr[n] = E;
}

// Pass A: k-pass row-window-filtered scatter of edge indices.
// pass = blockIdx.x / eblocks; only edges whose row falls in this pass's
// window are scattered. Window ~= perm_bytes/k -> L2-mergeable.
__global__ void fill_perm(const int* __restrict__ rows, int E, int eblocks, int k,
                          int n, int* __restrict__ cursor, int* __restrict__ perm) {
    int pass = blockIdx.x / eblocks;
    int e = (blockIdx.x - pass * eblocks) * blockDim.x + threadIdx.x;
    if (e >= E) return;
    int lo = (int)((long long)pass * n / k);
    int hi = (int)((long long)(pass + 1) * n / k);
    int r = rows[e];
    if (r >= lo && r < hi) {
        int p = atomicAdd(&cursor[r], 1);
        perm[p] = e;
    }
}

// Pass B: coalesced gather of packed (col, val) records in CSR order.
__global__ void fill_ev(const int* __restrict__ perm, const int* __restrict__ cols,
                        const float* __restrict__ vals, int E, int2* __restrict__ ev) {
    int t = blockIdx.x * blockDim.x + threadIdx.x;
    if (t < E) {
        int e = perm[t];
        ev[t] = make_int2(cols[e], __float_as_int(vals[e]));
    }
}

// ---------- SpMM layer 1 (4-deep pipelined) ----------
__global__ void spmm_l1(const int* __restrict__ row_ptr, const int2* __restrict__ ev,
                        const float* __restrict__ A, const float* __restrict__ B,
                        int nA, int n, float* __restrict__ f1) {
    long long t = (long long)blockIdx.x * blockDim.x + threadIdx.x;
    int r = (int)(t >> 6);
    int d = (int)(t & 63);
    if (r >= n) return;
    int beg = row_ptr[r], end = row_ptr[r + 1];
    float acc = 0.0f;
    int j = beg;
    for (; j + 4 <= end; j += 4) {
        int2 e0 = ev[j], e1 = ev[j + 1], e2 = ev[j + 2], e3 = ev[j + 3];
        const float* p0 = (e0.x < nA) ? A + (size_t)e0.x * D : B + (size_t)(e0.x - nA) * D;
        const float* p1 = (e1.x < nA) ? A + (size_t)e1.x * D : B + (size_t)(e1.x - nA) * D;
        const float* p2 = (e2.x < nA) ? A + (size_t)e2.x * D : B + (size_t)(e2.x - nA) * D;
        const float* p3 = (e3.x < nA) ? A + (size_t)e3.x * D : B + (size_t)(e3.x - nA) * D;
        float x0 = p0[d], x1 = p1[d], x2 = p2[d], x3 = p3[d];
        acc = fmaf(__int_as_float(e0.y), x0, acc);
        acc = fmaf(__int_as_float(e1.y), x1, acc);
        acc = fmaf(__int_as_float(e2.y), x2, acc);
        acc = fmaf(__int_as_float(e3.y), x3, acc);
    }
    for (; j < end; ++j) {
        int2 e = ev[j];
        const float* p = (e.x < nA) ? A + (size_t)e.x * D : B + (size_t)(e.x - nA) * D;
        acc = fmaf(__int_as_float(e.y), p[d], acc);
    }
    f1[(size_t)r * D + d] = acc;
}

// ---------- SpMM layer 2 fused with epilogue (4-deep pipelined) ----------
__global__ void spmm_l2_fin(const int* __restrict__ row_ptr, const int2* __restrict__ ev,
                            const float* __restrict__ f1,
                            const float* __restrict__ A, const float* __restrict__ B,
                            int nA, int n, float* __restrict__ out,
                            long long offA, long long offB) {
    long long t = (long long)blockIdx.x * blockDim.x + threadIdx.x;
    int r = (int)(t >> 6);
    int d = (int)(t & 63);
    if (r >= n) return;
    int beg = row_ptr[r], end = row_ptr[r + 1];
    float acc = 0.0f;
    int j = beg;
    for (; j + 4 <= end; j += 4) {
        int2 e0 = ev[j], e1 = ev[j + 1], e2 = ev[j + 2], e3 = ev[j + 3];
        float x0 = f1[(size_t)e0.x * D + d];
        float x1 = f1[(size_t)e1.x * D + d];
        float x2 = f1[(size_t)e2.x * D + d];
        float x3 = f1[(size_t)e3.x * D + d];
        acc = fmaf(__int_as_float(e0.y), x0, acc);
        acc = fmaf(__int_as_float(e1.y), x1, acc);
        acc = fmaf(__int_as_float(e2.y), x2, acc);
        acc = fmaf(__int_as_float(e3.y), x3, acc);
    }
    for (; j < end; ++j) {
        int2 e = ev[j];
        acc = fmaf(__int_as_float(e.y), f1[(size_t)e.x * D + d], acc);
    }
    float x1r = f1[(size_t)r * D + d];
    float s1 = x1r * x1r;
    float s2 = acc * acc;
    #pragma unroll
    for (int m = 32; m > 0; m >>= 1) {
        s1 += __shfl_xor(s1, m, 64);
        s2 += __shfl_xor(s2, m, 64);
    }
    float n1 = fmaxf(sqrtf(s1), 1e-12f);
    float n2 = fmaxf(sqrtf(s2), 1e-12f);
    float x0 = (r < nA) ? A[(size_t)r * D + d] : B[(size_t)(r - nA) * D + d];
    float y = (x0 + x1r / n1 + acc / n2) * (1.0f / 3.0f);
    long long orow = (r < nA) ? (offA + r) : (offB + (r - nA));
    out[orow * D + d] = y;
}

extern "C" void kernel_launch(void* const* d_in, const int* in_sizes, int n_in,
                              void* d_out, int out_size, void* d_ws, size_t ws_size,
                              hipStream_t stream) {
    const float* users   = (const float*)d_in[0];
    const float* items   = (const float*)d_in[1];
    const float* bundles = (const float*)d_in[2];
    const float* ui_vals = (const float*)d_in[3];
    const float* bi_vals = (const float*)d_in[4];
    const float* ub_vals = (const float*)d_in[5];
    const int* ui_rows = (const int*)d_in[6];
    const int* ui_cols = (const int*)d_in[7];
    const int* bi_rows = (const int*)d_in[8];
    const int* bi_cols = (const int*)d_in[9];
    const int* ub_rows = (const int*)d_in[10];
    const int* ub_cols = (const int*)d_in[11];

    const int U  = in_sizes[0] / D;
    const int NI = in_sizes[1] / D;
    const int NB = in_sizes[2] / D;
    const int E_ui = in_sizes[3];
    const int E_bi = in_sizes[4];
    const int E_ub = in_sizes[5];

    float* out = (float*)d_out;

    const int maxRows = U + NI;       // 150000
    const int maxE    = E_ui;         // 2M

    char* ws = (char*)d_ws;
    float* f1      = (float*)ws;  ws += (size_t)maxRows * D * sizeof(float); // 38.4 MB
    int2*  ev      = (int2*)ws;   ws += (size_t)maxE * sizeof(int2);         // 16 MB
    int*   perm    = (int*)ws;    ws += (size_t)maxE * sizeof(int);          // 8 MB
    int*   row_ptr = (int*)ws;    ws += (size_t)(maxRows + 1) * sizeof(int);
    int*   cursor  = (int*)ws;    ws += (size_t)maxRows * sizeof(int);
    int*   bsum    = (int*)ws;    ws += 1024 * sizeof(int);
    (void)ws_size;

    const long long off_UI_u = 0;
    const long long off_UB_u = U;
    const long long off_BI_b = 2LL * U;
    const long long off_UB_b = 2LL * U + NB;
    const long long off_UI_i = 2LL * U + 2LL * NB;
    const long long off_BI_i = 2LL * U + 2LL * NB + NI;

    auto run_prop = [&](const int* rows, const int* cols, const float* vals, int E,
                        const float* A, const float* B, int nA, int nB,
                        long long offA, long long offB, int k) {
        const int n = nA + nB;
        const int eblocks = (E + 255) / 256;
        const int nblocks = (n + 255) / 256;

        hipMemsetAsync(cursor, 0, (size_t)n * sizeof(int), stream);
        count_rows<<<eblocks, 256, 0, stream>>>(rows, E, cursor);
        scan_block<<<nblocks, 256, 0, stream>>>(cursor, n, row_ptr, bsum);
        scan_bsums<<<1, 1024, 0, stream>>>(bsum, nblocks);
        add_offsets<<<nblocks, 256, 0, stream>>>(row_ptr, bsum, n, E);
        hipMemcpyAsync(cursor, row_ptr, (size_t)n * sizeof(int),
                       hipMemcpyDeviceToDevice, stream);
        fill_perm<<<k * eblocks, 256, 0, stream>>>(rows, E, eblocks, k, n, cursor, perm);
        fill_ev<<<eblocks, 256, 0, stream>>>(perm, cols, vals, E, ev);

        const long long T = (long long)n * D;
        const int rblocks = (int)((T + 255) / 256);
        spmm_l1<<<rblocks, 256, 0, stream>>>(row_ptr, ev, A, B, nA, n, f1);
        spmm_l2_fin<<<rblocks, 256, 0, stream>>>(row_ptr, ev, f1, A, B, nA, n,
                                                 out, offA, offB);
    };

    // k chosen so the live perm write window ~= 2 MB (perm bytes / k)
    run_prop(ui_rows, ui_cols, ui_vals, E_ui, users, items, U, NI, off_UI_u, off_UI_i, 4);
    run_prop(bi_rows, bi_cols, bi_vals, E_bi, bundles, items, NB, NI, off_BI_b, off_BI_i, 2);
    run_prop(ub_rows, ub_cols, ub_vals, E_ub, users, bundles, U, NB, off_UB_u, off_UB_b, 2);
}